// Round 3
// baseline (855.339 us; speedup 1.0000x reference)
//
#include <hip/hip_runtime.h>

// GCN policy net: 2× GCNConv(H=16) + global max pool + linear head.
// Edge aggregation via coarse bucketing (256 dst-nodes per bucket):
//   k_bcount: LDS histogram of dst>>8          (one pass, 13 MB read)
//   k_bscan : exact bucket bases (aligned)
//   k_bin   : tile-local reorder -> packed u32 (dlow<<17)|src per bucket.
//             All writes of a tile complete within the tile's lifetime ->
//             full-line writebacks (fixes the 16x write amplification the
//             global CSR scatter had: a node's edges span the whole stream).
//   k_deg   : per-bucket LDS node histogram -> dis = rsqrt(deg+1)
//   k_bagg  : per-bucket LDS accumulator (256x16 f32), gather g[src] rows,
//             fused bias+relu. No per-node CSR needed at all.

#define FIN 128
#define HDIM 16
#define AOUT 10
#define NPB 256      // nodes per bucket (bucket = dst >> 8)
#define KMAX 400     // LDS sizing bound: supports n <= 102400
#define TILE 4096    // edges per k_bin tile

__global__ __launch_bounds__(256) void k_bcount(const int* __restrict__ dst, int E,
                                                int* __restrict__ bcnt, int K) {
    __shared__ int hist[KMAX];
    for (int i = threadIdx.x; i < K; i += 256) hist[i] = 0;
    __syncthreads();
    int stride = gridDim.x * 256;
    for (int e = blockIdx.x * 256 + threadIdx.x; e < E; e += stride)
        atomicAdd(&hist[dst[e] >> 8], 1);
    __syncthreads();
    for (int i = threadIdx.x; i < K; i += 256)
        if (hist[i]) atomicAdd(&bcnt[i], hist[i]);
}

// exact bucket bases, padded to 16 u32 (64B) alignment; init cursors
__global__ void k_bscan(const int* __restrict__ bcnt, int* __restrict__ bbase,
                        int* __restrict__ bcur, int K) {
    if (threadIdx.x == 0) {
        int run = 0;
        for (int b = 0; b < K; b++) {
            bbase[b] = run;
            bcur[b] = run;
            run += (bcnt[b] + 15) & ~15;
        }
        bbase[K] = run;
    }
}

__global__ __launch_bounds__(256) void k_bin(const int* __restrict__ src,
                                             const int* __restrict__ dst, int E,
                                             int* __restrict__ bcur,
                                             unsigned int* __restrict__ pairs, int K) {
    __shared__ int hist[KMAX], gbase[KMAX], run[KMAX];
    int t = threadIdx.x;
    int e0 = blockIdx.x * TILE;
    int e1 = min(E, e0 + TILE);
    for (int i = t; i < K; i += 256) { hist[i] = 0; run[i] = 0; }
    __syncthreads();
    for (int e = e0 + t; e < e1; e += 256) atomicAdd(&hist[dst[e] >> 8], 1);
    __syncthreads();
    for (int b = t; b < K; b += 256)
        if (hist[b]) gbase[b] = atomicAdd(&bcur[b], hist[b]);
    __syncthreads();
    for (int e = e0 + t; e < e1; e += 256) {
        int d = dst[e], s = src[e], b = d >> 8;
        int r = atomicAdd(&run[b], 1);
        pairs[gbase[b] + r] = (unsigned)s | ((unsigned)(d & 255) << 17);
    }
}

// per-bucket node in-degree -> dis = rsqrt(deg+1)
__global__ __launch_bounds__(256) void k_deg(const unsigned int* __restrict__ pairs,
                                             const int* __restrict__ bbase,
                                             const int* __restrict__ bcnt,
                                             float* __restrict__ dis, int n) {
    __shared__ int cnt[NPB];
    int b = blockIdx.x, t = threadIdx.x;
    cnt[t] = 0;
    __syncthreads();
    int base = bbase[b], m = bcnt[b];
    for (int j = t; j < m; j += 256) atomicAdd(&cnt[pairs[base + j] >> 17], 1);
    __syncthreads();
    int node = (b << 8) + t;
    if (node < n) dis[node] = rsqrtf((float)(cnt[t] + 1));
}

// g[n][c] = dis[n] * sum_k x[n][k] * W1[k][c]      (x: [n,128], W1: [128,16])
__global__ __launch_bounds__(256) void k_gemm1(const float* __restrict__ x,
                                               const float* __restrict__ W1,
                                               const float* __restrict__ dis,
                                               float* __restrict__ g, int n) {
    __shared__ float Ws[FIN * HDIM];
    for (int i = threadIdx.x; i < FIN * HDIM; i += 256) Ws[i] = W1[i];
    __syncthreads();
    int t = threadIdx.x;
    int node = blockIdx.x * 16 + (t >> 4);
    int c = t & 15;
    if (node >= n) return;
    const float* xr = x + (size_t)node * FIN;
    float acc = 0.f;
#pragma unroll
    for (int k = 0; k < FIN; k += 4) {
        float4 xv = *reinterpret_cast<const float4*>(xr + k);
        acc += xv.x * Ws[(k + 0) * HDIM + c];
        acc += xv.y * Ws[(k + 1) * HDIM + c];
        acc += xv.z * Ws[(k + 2) * HDIM + c];
        acc += xv.w * Ws[(k + 3) * HDIM + c];
    }
    g[(size_t)node * HDIM + c] = dis[node] * acc;
}

// per-bucket aggregation: h[n][c] = relu(dis[n]*(acc[n][c] + g[n][c]) + bias[c])
__global__ __launch_bounds__(512) void k_bagg(const float* __restrict__ g,
                                              const unsigned int* __restrict__ pairs,
                                              const int* __restrict__ bbase,
                                              const int* __restrict__ bcnt,
                                              const float* __restrict__ dis,
                                              const float* __restrict__ bias,
                                              float* __restrict__ h, int n) {
    __shared__ float acc[NPB * HDIM];  // 16 KB
    int t = threadIdx.x, b = blockIdx.x;
    for (int i = t; i < NPB * HDIM; i += 512) acc[i] = 0.f;
    __syncthreads();
    int grp = t >> 4, c = t & 15;   // 32 groups of 16 lanes; one edge per group
    int base = bbase[b], m = bcnt[b];
    for (int j = grp; j < m; j += 32) {
        unsigned p = pairs[base + j];
        int s = p & 0x1FFFF, dl = p >> 17;
        atomicAdd(&acc[(dl << 4) + c], g[((size_t)s << 4) + c]);
    }
    __syncthreads();
    for (int i = t; i < NPB * HDIM; i += 512) {
        int node = (b << 8) + (i >> 4);
        if (node < n) {
            int cc = i & 15;
            float v = dis[node] * (acc[i] + g[((size_t)node << 4) + cc]) + bias[cc];
            h[((size_t)node << 4) + cc] = fmaxf(v, 0.f);
        }
    }
}

// g2[n][c] = dis[n] * sum_j h[n][j] * W2[j][c]   (W2: [16,16])
__global__ __launch_bounds__(256) void k_gemm2(const float* __restrict__ h,
                                               const float* __restrict__ W2,
                                               const float* __restrict__ dis,
                                               float* __restrict__ g, int n) {
    __shared__ float Ws[HDIM * HDIM];
    if (threadIdx.x < HDIM * HDIM) Ws[threadIdx.x] = W2[threadIdx.x];
    __syncthreads();
    int t = threadIdx.x;
    int node = blockIdx.x * 16 + (t >> 4);
    int c = t & 15;
    if (node >= n) return;
    const float* hr = h + (size_t)node * HDIM;
    float acc = 0.f;
#pragma unroll
    for (int j = 0; j < HDIM; j++) acc += hr[j] * Ws[j * HDIM + c];
    g[(size_t)node * HDIM + c] = dis[node] * acc;
}

// global max pool over nodes (h >= 0 after relu, so uint atomicMax works)
__global__ __launch_bounds__(256) void k_maxpool(const float* __restrict__ h,
                                                 unsigned int* __restrict__ pooled, int n) {
    int t = threadIdx.x;
    int c = t & 15;
    int grp = t >> 4;  // 16 groups per block
    float m = 0.f;
    for (int node = blockIdx.x * 16 + grp; node < n; node += gridDim.x * 16)
        m = fmaxf(m, h[(size_t)node * HDIM + c]);
    __shared__ float s[256];
    s[t] = m;
    __syncthreads();
    for (int d = 128; d >= 16; d >>= 1) {
        if (t < d) s[t] = fmaxf(s[t], s[t + d]);
        __syncthreads();
    }
    if (t < 16) atomicMax(&pooled[t], __float_as_uint(s[t]));
}

// out[a] = sum_c pooled[c] * Wc[c][a] + bc[a]   (Wc: [16,10])
__global__ void k_final(const unsigned int* __restrict__ pooled, const float* __restrict__ Wc,
                        const float* __restrict__ bc, float* __restrict__ out) {
    __shared__ float p[HDIM];
    int t = threadIdx.x;
    if (t < HDIM) p[t] = __uint_as_float(pooled[t]);
    __syncthreads();
    if (t < AOUT) {
        float acc = bc[t];
#pragma unroll
        for (int c = 0; c < HDIM; c++) acc += p[c] * Wc[c * AOUT + t];
        out[t] = acc;
    }
}

extern "C" void kernel_launch(void* const* d_in, const int* in_sizes, int n_in,
                              void* d_out, int out_size, void* d_ws, size_t ws_size,
                              hipStream_t stream) {
    const float* x  = (const float*)d_in[0];
    const int*   ei = (const int*)d_in[1];
    const float* W1 = (const float*)d_in[2];
    const float* b1 = (const float*)d_in[3];
    const float* W2 = (const float*)d_in[4];
    const float* b2 = (const float*)d_in[5];
    const float* Wc = (const float*)d_in[6];
    const float* bc = (const float*)d_in[7];
    float* out = (float*)d_out;

    int n = in_sizes[0] / FIN;
    int E = in_sizes[1] / 2;
    const int* srcp = ei;       // edge_index[0]
    const int* dstp = ei + E;   // edge_index[1]
    int K = (n + NPB - 1) / NPB;   // 391 for n=100000

    char* ws = (char*)d_ws;
    auto alloc = [&](size_t bytes) -> char* {
        char* p = ws;
        ws += (bytes + 255) & ~(size_t)255;
        return p;
    };
    float*        dis   = (float*)alloc((size_t)n * 4);
    int*          bcnt  = (int*)alloc((size_t)(K + 1) * 4);
    int*          bbase = (int*)alloc((size_t)(K + 1) * 4);
    int*          bcur  = (int*)alloc((size_t)K * 4);
    unsigned int* pairs = (unsigned int*)alloc(((size_t)E + (size_t)(K + 1) * 16) * 4);
    float*        g     = (float*)alloc((size_t)n * HDIM * 4);
    float*        h     = (float*)alloc((size_t)n * HDIM * 4);
    unsigned int* pooled= (unsigned int*)alloc(64);

    hipMemsetAsync(bcnt, 0, (size_t)(K + 1) * 4, stream);
    hipMemsetAsync(pooled, 0, 64, stream);

    k_bcount<<<512, 256, 0, stream>>>(dstp, E, bcnt, K);
    k_bscan<<<1, 64, 0, stream>>>(bcnt, bbase, bcur, K);
    k_bin<<<(E + TILE - 1) / TILE, 256, 0, stream>>>(srcp, dstp, E, bcur, pairs, K);
    k_deg<<<K, 256, 0, stream>>>(pairs, bbase, bcnt, dis, n);

    k_gemm1<<<(n + 15) / 16, 256, 0, stream>>>(x, W1, dis, g, n);
    k_bagg<<<K, 512, 0, stream>>>(g, pairs, bbase, bcnt, dis, b1, h, n);
    k_gemm2<<<(n + 15) / 16, 256, 0, stream>>>(h, W2, dis, g, n);
    k_bagg<<<K, 512, 0, stream>>>(g, pairs, bbase, bcnt, dis, b2, h, n);

    k_maxpool<<<256, 256, 0, stream>>>(h, pooled, n);
    k_final<<<1, 64, 0, stream>>>(pooled, Wc, bc, out);
}

// Round 4
// 266.359 us; speedup vs baseline: 3.2112x; 3.2112x over previous
//
#include <hip/hip_runtime.h>

// GCN policy net: 2× GCNConv(H=16) + global max pool + linear head.
// Build: coarse bucketing (256 dst/bucket) with tile-local scatter (full-line
// writebacks), then per-bucket counting sort -> compact node-ordered CSR.
// Aggregate: one wave per node, 16 edge-slots x 4 lanes (float4 piece) =
// 16 gathers in flight per wave, shfl_xor reduce, fused dis/bias/relu.

#define FIN 128
#define HDIM 16
#define AOUT 10
#define NPB 256      // nodes per bucket (bucket = dst >> 8)
#define KMAX 400     // LDS sizing bound: supports n <= 102400
#define TILE 4096    // edges per k_bin tile

__global__ __launch_bounds__(256) void k_bcount(const int* __restrict__ dst, int E,
                                                int* __restrict__ bcnt, int K) {
    __shared__ int hist[KMAX];
    for (int i = threadIdx.x; i < K; i += 256) hist[i] = 0;
    __syncthreads();
    int stride = gridDim.x * 256;
    for (int e = blockIdx.x * 256 + threadIdx.x; e < E; e += stride)
        atomicAdd(&hist[dst[e] >> 8], 1);
    __syncthreads();
    for (int i = threadIdx.x; i < K; i += 256)
        if (hist[i]) atomicAdd(&bcnt[i], hist[i]);
}

// bucket bases: padded (pairs) + exact (srcidx); init cursors; off[n] sentinel
__global__ __launch_bounds__(256) void k_bscan(const int* __restrict__ bcnt,
                                               int* __restrict__ pbase,
                                               int* __restrict__ ebase,
                                               int* __restrict__ bcur,
                                               int* __restrict__ off,
                                               int K, int n, int E) {
    __shared__ int sc[KMAX], sp[KMAX], se[KMAX];
    int t = threadIdx.x;
    for (int i = t; i < K; i += 256) sc[i] = bcnt[i];
    __syncthreads();
    if (t == 0) {
        int rp = 0, re = 0;
        for (int b = 0; b < K; b++) {
            sp[b] = rp; se[b] = re;
            rp += (sc[b] + 15) & ~15;
            re += sc[b];
        }
        off[n] = E;
    }
    __syncthreads();
    for (int i = t; i < K; i += 256) {
        pbase[i] = sp[i];
        bcur[i]  = sp[i];
        ebase[i] = se[i];
    }
}

// tile-local reorder -> packed u32 (dlow<<17)|src into bucket regions
__global__ __launch_bounds__(256) void k_bin(const int* __restrict__ src,
                                             const int* __restrict__ dst, int E,
                                             int* __restrict__ bcur,
                                             unsigned int* __restrict__ pairs, int K) {
    __shared__ int hist[KMAX], gbase[KMAX], run[KMAX];
    int t = threadIdx.x;
    int e0 = blockIdx.x * TILE;
    int e1 = min(E, e0 + TILE);
    for (int i = t; i < K; i += 256) { hist[i] = 0; run[i] = 0; }
    __syncthreads();
    for (int e = e0 + t; e < e1; e += 256) atomicAdd(&hist[dst[e] >> 8], 1);
    __syncthreads();
    for (int b = t; b < K; b += 256)
        if (hist[b]) gbase[b] = atomicAdd(&bcur[b], hist[b]);
    __syncthreads();
    for (int e = e0 + t; e < e1; e += 256) {
        int d = dst[e], s = src[e], b = d >> 8;
        int r = atomicAdd(&run[b], 1);
        pairs[gbase[b] + r] = (unsigned)s | ((unsigned)(d & 255) << 17);
    }
}

// per-bucket counting sort: pairs -> compact node-ordered srcidx + off + dis
__global__ __launch_bounds__(256) void k_sort(const unsigned int* __restrict__ pairs,
                                              const int* __restrict__ pbase,
                                              const int* __restrict__ ebase,
                                              const int* __restrict__ bcnt,
                                              int* __restrict__ srcidx,
                                              int* __restrict__ off,
                                              float* __restrict__ dis, int n) {
    __shared__ int cnt[NPB], pre[NPB], cur[NPB];
    int b = blockIdx.x, t = threadIdx.x;
    cnt[t] = 0;
    __syncthreads();
    int base = pbase[b], m = bcnt[b], eb = ebase[b];
    for (int j = t; j < m; j += 256) atomicAdd(&cnt[pairs[base + j] >> 17], 1);
    __syncthreads();
    int v = cnt[t];
    pre[t] = v;
    for (int d = 1; d < 256; d <<= 1) {
        __syncthreads();
        int add = (t >= d) ? pre[t - d] : 0;
        __syncthreads();
        pre[t] += add;
    }
    __syncthreads();
    int excl = pre[t] - v;
    cur[t] = excl;
    int node = (b << 8) + t;
    if (node < n) {
        off[node] = eb + excl;
        dis[node] = rsqrtf((float)(v + 1));
    }
    __syncthreads();
    for (int j = t; j < m; j += 256) {
        unsigned p = pairs[base + j];
        int pos = eb + atomicAdd(&cur[p >> 17], 1);
        srcidx[pos] = (int)(p & 0x1FFFF);
    }
}

// g[n][c] = dis[n] * sum_k x[n][k] * W1[k][c]      (x: [n,128], W1: [128,16])
__global__ __launch_bounds__(256) void k_gemm1(const float* __restrict__ x,
                                               const float* __restrict__ W1,
                                               const float* __restrict__ dis,
                                               float* __restrict__ g, int n) {
    __shared__ float Ws[FIN * HDIM];
    for (int i = threadIdx.x; i < FIN * HDIM; i += 256) Ws[i] = W1[i];
    __syncthreads();
    int t = threadIdx.x;
    int node = blockIdx.x * 16 + (t >> 4);
    int c = t & 15;
    if (node >= n) return;
    const float* xr = x + (size_t)node * FIN;
    float acc = 0.f;
#pragma unroll
    for (int k = 0; k < FIN; k += 4) {
        float4 xv = *reinterpret_cast<const float4*>(xr + k);
        acc += xv.x * Ws[(k + 0) * HDIM + c];
        acc += xv.y * Ws[(k + 1) * HDIM + c];
        acc += xv.z * Ws[(k + 2) * HDIM + c];
        acc += xv.w * Ws[(k + 3) * HDIM + c];
    }
    g[(size_t)node * HDIM + c] = dis[node] * acc;
}

// one wave per node; lane = slot*4+piece. 16 edge-slots, each 4 lanes load a
// float4 piece of the 64B g row. h[n] = relu(dis[n]*(g[n]+sum g[src]) + b)
__global__ __launch_bounds__(256) void k_agg(const float4* __restrict__ g4,
                                             const int* __restrict__ off,
                                             const int* __restrict__ srcidx,
                                             const float* __restrict__ dis,
                                             const float4* __restrict__ bias4,
                                             float4* __restrict__ h4, int n) {
    int t = threadIdx.x;
    int lane = t & 63;
    int node = blockIdx.x * 4 + (t >> 6);
    if (node >= n) return;
    int slot = lane >> 2, piece = lane & 3;
    int e0 = off[node], e1 = off[node + 1];
    float4 a = make_float4(0.f, 0.f, 0.f, 0.f);
    for (int e = e0 + slot; e < e1; e += 16) {
        int s = srcidx[e];
        float4 v = g4[(size_t)s * 4 + piece];
        a.x += v.x; a.y += v.y; a.z += v.z; a.w += v.w;
    }
    if (slot == 0) {  // self-loop term
        float4 v = g4[(size_t)node * 4 + piece];
        a.x += v.x; a.y += v.y; a.z += v.z; a.w += v.w;
    }
#pragma unroll
    for (int d = 4; d <= 32; d <<= 1) {
        a.x += __shfl_xor(a.x, d);
        a.y += __shfl_xor(a.y, d);
        a.z += __shfl_xor(a.z, d);
        a.w += __shfl_xor(a.w, d);
    }
    if (lane < 4) {  // piece == lane
        float dn = dis[node];
        float4 bb = bias4[lane];
        float4 o;
        o.x = fmaxf(dn * a.x + bb.x, 0.f);
        o.y = fmaxf(dn * a.y + bb.y, 0.f);
        o.z = fmaxf(dn * a.z + bb.z, 0.f);
        o.w = fmaxf(dn * a.w + bb.w, 0.f);
        h4[(size_t)node * 4 + lane] = o;
    }
}

// g2[n][c] = dis[n] * sum_j h[n][j] * W2[j][c]   (W2: [16,16])
__global__ __launch_bounds__(256) void k_gemm2(const float* __restrict__ h,
                                               const float* __restrict__ W2,
                                               const float* __restrict__ dis,
                                               float* __restrict__ g, int n) {
    __shared__ float Ws[HDIM * HDIM];
    if (threadIdx.x < HDIM * HDIM) Ws[threadIdx.x] = W2[threadIdx.x];
    __syncthreads();
    int t = threadIdx.x;
    int node = blockIdx.x * 16 + (t >> 4);
    int c = t & 15;
    if (node >= n) return;
    const float* hr = h + (size_t)node * HDIM;
    float acc = 0.f;
#pragma unroll
    for (int j = 0; j < HDIM; j++) acc += hr[j] * Ws[j * HDIM + c];
    g[(size_t)node * HDIM + c] = dis[node] * acc;
}

// global max pool over nodes (h >= 0 after relu, so uint atomicMax works)
__global__ __launch_bounds__(256) void k_maxpool(const float* __restrict__ h,
                                                 unsigned int* __restrict__ pooled, int n) {
    int t = threadIdx.x;
    int c = t & 15;
    int grp = t >> 4;  // 16 groups per block
    float m = 0.f;
    for (int node = blockIdx.x * 16 + grp; node < n; node += gridDim.x * 16)
        m = fmaxf(m, h[(size_t)node * HDIM + c]);
    __shared__ float s[256];
    s[t] = m;
    __syncthreads();
    for (int d = 128; d >= 16; d >>= 1) {
        if (t < d) s[t] = fmaxf(s[t], s[t + d]);
        __syncthreads();
    }
    if (t < 16) atomicMax(&pooled[t], __float_as_uint(s[t]));
}

// out[a] = sum_c pooled[c] * Wc[c][a] + bc[a]   (Wc: [16,10])
__global__ void k_final(const unsigned int* __restrict__ pooled, const float* __restrict__ Wc,
                        const float* __restrict__ bc, float* __restrict__ out) {
    __shared__ float p[HDIM];
    int t = threadIdx.x;
    if (t < HDIM) p[t] = __uint_as_float(pooled[t]);
    __syncthreads();
    if (t < AOUT) {
        float acc = bc[t];
#pragma unroll
        for (int c = 0; c < HDIM; c++) acc += p[c] * Wc[c * AOUT + t];
        out[t] = acc;
    }
}

extern "C" void kernel_launch(void* const* d_in, const int* in_sizes, int n_in,
                              void* d_out, int out_size, void* d_ws, size_t ws_size,
                              hipStream_t stream) {
    const float* x  = (const float*)d_in[0];
    const int*   ei = (const int*)d_in[1];
    const float* W1 = (const float*)d_in[2];
    const float* b1 = (const float*)d_in[3];
    const float* W2 = (const float*)d_in[4];
    const float* b2 = (const float*)d_in[5];
    const float* Wc = (const float*)d_in[6];
    const float* bc = (const float*)d_in[7];
    float* out = (float*)d_out;

    int n = in_sizes[0] / FIN;
    int E = in_sizes[1] / 2;
    const int* srcp = ei;       // edge_index[0]
    const int* dstp = ei + E;   // edge_index[1]
    int K = (n + NPB - 1) / NPB;   // 391 for n=100000

    char* ws = (char*)d_ws;
    auto alloc = [&](size_t bytes) -> char* {
        char* p = ws;
        ws += (bytes + 255) & ~(size_t)255;
        return p;
    };
    float*        dis   = (float*)alloc((size_t)n * 4);
    int*          bcnt  = (int*)alloc((size_t)K * 4);
    int*          pbase = (int*)alloc((size_t)K * 4);
    int*          ebase = (int*)alloc((size_t)K * 4);
    int*          bcur  = (int*)alloc((size_t)K * 4);
    int*          off   = (int*)alloc((size_t)(n + 1) * 4);
    unsigned int* pairs = (unsigned int*)alloc(((size_t)E + (size_t)K * 16) * 4);
    int*          srcidx= (int*)alloc((size_t)E * 4);
    float*        g     = (float*)alloc((size_t)n * HDIM * 4);
    float*        h     = (float*)alloc((size_t)n * HDIM * 4);
    unsigned int* pooled= (unsigned int*)alloc(64);

    hipMemsetAsync(bcnt, 0, (size_t)K * 4, stream);
    hipMemsetAsync(pooled, 0, 64, stream);

    k_bcount<<<512, 256, 0, stream>>>(dstp, E, bcnt, K);
    k_bscan<<<1, 256, 0, stream>>>(bcnt, pbase, ebase, bcur, off, K, n, E);
    k_bin<<<(E + TILE - 1) / TILE, 256, 0, stream>>>(srcp, dstp, E, bcur, pairs, K);
    k_sort<<<K, 256, 0, stream>>>(pairs, pbase, ebase, bcnt, srcidx, off, dis, n);

    k_gemm1<<<(n + 15) / 16, 256, 0, stream>>>(x, W1, dis, g, n);
    k_agg<<<(n + 3) / 4, 256, 0, stream>>>((const float4*)g, off, srcidx, dis,
                                           (const float4*)b1, (float4*)h, n);
    k_gemm2<<<(n + 15) / 16, 256, 0, stream>>>(h, W2, dis, g, n);
    k_agg<<<(n + 3) / 4, 256, 0, stream>>>((const float4*)g, off, srcidx, dis,
                                           (const float4*)b2, (float4*)h, n);

    k_maxpool<<<256, 256, 0, stream>>>(h, pooled, n);
    k_final<<<1, 64, 0, stream>>>(pooled, Wc, bc, out);
}

// Round 5
// 243.000 us; speedup vs baseline: 3.5199x; 1.0961x over previous
//
#include <hip/hip_runtime.h>

// GCN policy net: 2× GCNConv(H=16) + global max pool + linear head.
// Build: coarse bucketing (256 dst/bucket). k_bin stages the reorder in LDS
// (bucket-sorted tile buffer) and writes out linearly -> coalesced full-line
// global writes (the round-3 version did 3.2M random 4B global stores, 6x
// write amplification). Then per-bucket counting sort -> node-ordered CSR.
// Aggregate: one wave per node, 16 edge-slots x 4 lanes (float4 piece),
// shfl_xor reduce, fused dis/bias/relu.

#define FIN 128
#define HDIM 16
#define AOUT 10
#define NPB 256      // nodes per bucket (bucket = dst >> 8)
#define KMAX 512     // LDS sizing bound (padded): supports n <= 131072
#define TILE 4096    // edges per k_bin tile

__global__ __launch_bounds__(256) void k_bcount(const int* __restrict__ dst, int E,
                                                int* __restrict__ bcnt, int K) {
    __shared__ int hist[KMAX];
    for (int i = threadIdx.x; i < K; i += 256) hist[i] = 0;
    __syncthreads();
    int stride = gridDim.x * 1024;
    for (int e = (blockIdx.x * 256 + threadIdx.x) * 4; e < E; e += stride) {
        if (e + 4 <= E) {
            int4 d4 = *reinterpret_cast<const int4*>(dst + e);
            atomicAdd(&hist[d4.x >> 8], 1);
            atomicAdd(&hist[d4.y >> 8], 1);
            atomicAdd(&hist[d4.z >> 8], 1);
            atomicAdd(&hist[d4.w >> 8], 1);
        } else {
            for (int q = e; q < E; q++) atomicAdd(&hist[dst[q] >> 8], 1);
        }
    }
    __syncthreads();
    for (int i = threadIdx.x; i < K; i += 256)
        if (hist[i]) atomicAdd(&bcnt[i], hist[i]);
}

// bucket bases: padded (pairs) + exact (srcidx); init cursors; off[n] sentinel
__global__ __launch_bounds__(256) void k_bscan(const int* __restrict__ bcnt,
                                               int* __restrict__ pbase,
                                               int* __restrict__ ebase,
                                               int* __restrict__ bcur,
                                               int* __restrict__ off,
                                               int K, int n, int E) {
    __shared__ int sc[KMAX], sp[KMAX], se[KMAX];
    int t = threadIdx.x;
    for (int i = t; i < K; i += 256) sc[i] = bcnt[i];
    __syncthreads();
    if (t == 0) {
        int rp = 0, re = 0;
        for (int b = 0; b < K; b++) {
            sp[b] = rp; se[b] = re;
            rp += (sc[b] + 15) & ~15;
            re += sc[b];
        }
        off[n] = E;
    }
    __syncthreads();
    for (int i = t; i < K; i += 256) {
        pbase[i] = sp[i];
        bcur[i]  = sp[i];
        ebase[i] = se[i];
    }
}

// tile-local reorder: histogram -> LDS scan -> bucket-sorted LDS buffer ->
// linear coalesced copy-out to per-bucket global windows.
__global__ __launch_bounds__(256) void k_bin(const int* __restrict__ src,
                                             const int* __restrict__ dst, int E,
                                             int* __restrict__ bcur,
                                             unsigned int* __restrict__ pairs, int K) {
    __shared__ int hist[KMAX], lofs[KMAX], run[KMAX], gbase[KMAX], ss[256];
    __shared__ unsigned int buf[TILE];
    __shared__ unsigned short bkt[TILE];
    int t = threadIdx.x;
    int e0 = blockIdx.x * TILE;
    int e1 = min(E, e0 + TILE);
    for (int i = t; i < KMAX; i += 256) hist[i] = 0;
    __syncthreads();
    // phase 1: tile histogram
    for (int e = e0 + t * 4; e < e1; e += 1024) {
        if (e + 4 <= e1) {
            int4 d4 = *reinterpret_cast<const int4*>(dst + e);
            atomicAdd(&hist[d4.x >> 8], 1);
            atomicAdd(&hist[d4.y >> 8], 1);
            atomicAdd(&hist[d4.z >> 8], 1);
            atomicAdd(&hist[d4.w >> 8], 1);
        } else {
            for (int q = e; q < e1; q++) atomicAdd(&hist[dst[q] >> 8], 1);
        }
    }
    __syncthreads();
    // phase 2: exclusive scan over padded 512 (2 entries per thread)
    int a0 = hist[2 * t], a1 = hist[2 * t + 1];
    int psum = a0 + a1;
    ss[t] = psum;
    for (int d = 1; d < 256; d <<= 1) {
        __syncthreads();
        int add = (t >= d) ? ss[t - d] : 0;
        __syncthreads();
        ss[t] += add;
    }
    __syncthreads();
    int excl = ss[t] - psum;
    lofs[2 * t] = excl;     run[2 * t] = excl;
    lofs[2 * t + 1] = excl + a0; run[2 * t + 1] = excl + a0;
    __syncthreads();
    // reserve global windows (one atomic per non-empty bucket)
    for (int b = t; b < K; b += 256)
        if (hist[b]) gbase[b] = atomicAdd(&bcur[b], hist[b]);
    __syncthreads();
    // phase 3: scatter into bucket-sorted LDS buffer
    for (int e = e0 + t * 4; e < e1; e += 1024) {
        if (e + 4 <= e1) {
            int4 d4 = *reinterpret_cast<const int4*>(dst + e);
            int4 s4 = *reinterpret_cast<const int4*>(src + e);
            int b, r;
            b = d4.x >> 8; r = atomicAdd(&run[b], 1);
            buf[r] = (unsigned)s4.x | ((unsigned)(d4.x & 255) << 17); bkt[r] = (unsigned short)b;
            b = d4.y >> 8; r = atomicAdd(&run[b], 1);
            buf[r] = (unsigned)s4.y | ((unsigned)(d4.y & 255) << 17); bkt[r] = (unsigned short)b;
            b = d4.z >> 8; r = atomicAdd(&run[b], 1);
            buf[r] = (unsigned)s4.z | ((unsigned)(d4.z & 255) << 17); bkt[r] = (unsigned short)b;
            b = d4.w >> 8; r = atomicAdd(&run[b], 1);
            buf[r] = (unsigned)s4.w | ((unsigned)(d4.w & 255) << 17); bkt[r] = (unsigned short)b;
        } else {
            for (int q = e; q < e1; q++) {
                int d = dst[q], s = src[q], b = d >> 8;
                int r = atomicAdd(&run[b], 1);
                buf[r] = (unsigned)s | ((unsigned)(d & 255) << 17);
                bkt[r] = (unsigned short)b;
            }
        }
    }
    __syncthreads();
    // phase 4: linear coalesced copy-out
    int m = e1 - e0;
    for (int i = t; i < m; i += 256) {
        int b = bkt[i];
        pairs[gbase[b] + i - lofs[b]] = buf[i];
    }
}

// per-bucket counting sort: pairs -> compact node-ordered srcidx + off + dis
__global__ __launch_bounds__(256) void k_sort(const unsigned int* __restrict__ pairs,
                                              const int* __restrict__ pbase,
                                              const int* __restrict__ ebase,
                                              const int* __restrict__ bcnt,
                                              int* __restrict__ srcidx,
                                              int* __restrict__ off,
                                              float* __restrict__ dis, int n) {
    __shared__ int cnt[NPB], pre[NPB], cur[NPB];
    int b = blockIdx.x, t = threadIdx.x;
    cnt[t] = 0;
    __syncthreads();
    int base = pbase[b], m = bcnt[b], eb = ebase[b];
    for (int j = t; j < m; j += 256) atomicAdd(&cnt[pairs[base + j] >> 17], 1);
    __syncthreads();
    int v = cnt[t];
    pre[t] = v;
    for (int d = 1; d < 256; d <<= 1) {
        __syncthreads();
        int add = (t >= d) ? pre[t - d] : 0;
        __syncthreads();
        pre[t] += add;
    }
    __syncthreads();
    int excl = pre[t] - v;
    cur[t] = excl;
    int node = (b << 8) + t;
    if (node < n) {
        off[node] = eb + excl;
        dis[node] = rsqrtf((float)(v + 1));
    }
    __syncthreads();
    for (int j = t; j < m; j += 256) {
        unsigned p = pairs[base + j];
        int pos = eb + atomicAdd(&cur[p >> 17], 1);
        srcidx[pos] = (int)(p & 0x1FFFF);
    }
}

// g[n][c] = dis[n] * sum_k x[n][k] * W1[k][c]      (x: [n,128], W1: [128,16])
__global__ __launch_bounds__(256) void k_gemm1(const float* __restrict__ x,
                                               const float* __restrict__ W1,
                                               const float* __restrict__ dis,
                                               float* __restrict__ g, int n) {
    __shared__ float Ws[FIN * HDIM];
    for (int i = threadIdx.x; i < FIN * HDIM; i += 256) Ws[i] = W1[i];
    __syncthreads();
    int t = threadIdx.x;
    int node = blockIdx.x * 16 + (t >> 4);
    int c = t & 15;
    if (node >= n) return;
    const float* xr = x + (size_t)node * FIN;
    float acc = 0.f;
#pragma unroll
    for (int k = 0; k < FIN; k += 4) {
        float4 xv = *reinterpret_cast<const float4*>(xr + k);
        acc += xv.x * Ws[(k + 0) * HDIM + c];
        acc += xv.y * Ws[(k + 1) * HDIM + c];
        acc += xv.z * Ws[(k + 2) * HDIM + c];
        acc += xv.w * Ws[(k + 3) * HDIM + c];
    }
    g[(size_t)node * HDIM + c] = dis[node] * acc;
}

// one wave per node; lane = slot*4+piece. 16 edge-slots, each 4 lanes load a
// float4 piece of the 64B g row. h[n] = relu(dis[n]*(g[n]+sum g[src]) + b)
__global__ __launch_bounds__(256) void k_agg(const float4* __restrict__ g4,
                                             const int* __restrict__ off,
                                             const int* __restrict__ srcidx,
                                             const float* __restrict__ dis,
                                             const float4* __restrict__ bias4,
                                             float4* __restrict__ h4, int n) {
    int t = threadIdx.x;
    int lane = t & 63;
    int node = blockIdx.x * 4 + (t >> 6);
    if (node >= n) return;
    int slot = lane >> 2, piece = lane & 3;
    int e0 = off[node], e1 = off[node + 1];
    float4 a = make_float4(0.f, 0.f, 0.f, 0.f);
    for (int e = e0 + slot; e < e1; e += 16) {
        int s = srcidx[e];
        float4 v = g4[(size_t)s * 4 + piece];
        a.x += v.x; a.y += v.y; a.z += v.z; a.w += v.w;
    }
    if (slot == 0) {  // self-loop term
        float4 v = g4[(size_t)node * 4 + piece];
        a.x += v.x; a.y += v.y; a.z += v.z; a.w += v.w;
    }
#pragma unroll
    for (int d = 4; d <= 32; d <<= 1) {
        a.x += __shfl_xor(a.x, d);
        a.y += __shfl_xor(a.y, d);
        a.z += __shfl_xor(a.z, d);
        a.w += __shfl_xor(a.w, d);
    }
    if (lane < 4) {  // piece == lane
        float dn = dis[node];
        float4 bb = bias4[lane];
        float4 o;
        o.x = fmaxf(dn * a.x + bb.x, 0.f);
        o.y = fmaxf(dn * a.y + bb.y, 0.f);
        o.z = fmaxf(dn * a.z + bb.z, 0.f);
        o.w = fmaxf(dn * a.w + bb.w, 0.f);
        h4[(size_t)node * 4 + lane] = o;
    }
}

// g2[n][c] = dis[n] * sum_j h[n][j] * W2[j][c]   (W2: [16,16])
__global__ __launch_bounds__(256) void k_gemm2(const float* __restrict__ h,
                                               const float* __restrict__ W2,
                                               const float* __restrict__ dis,
                                               float* __restrict__ g, int n) {
    __shared__ float Ws[HDIM * HDIM];
    if (threadIdx.x < HDIM * HDIM) Ws[threadIdx.x] = W2[threadIdx.x];
    __syncthreads();
    int t = threadIdx.x;
    int node = blockIdx.x * 16 + (t >> 4);
    int c = t & 15;
    if (node >= n) return;
    const float* hr = h + (size_t)node * HDIM;
    float acc = 0.f;
#pragma unroll
    for (int j = 0; j < HDIM; j++) acc += hr[j] * Ws[j * HDIM + c];
    g[(size_t)node * HDIM + c] = dis[node] * acc;
}

// global max pool over nodes (h >= 0 after relu, so uint atomicMax works)
__global__ __launch_bounds__(256) void k_maxpool(const float* __restrict__ h,
                                                 unsigned int* __restrict__ pooled, int n) {
    int t = threadIdx.x;
    int c = t & 15;
    int grp = t >> 4;  // 16 groups per block
    float m = 0.f;
    for (int node = blockIdx.x * 16 + grp; node < n; node += gridDim.x * 16)
        m = fmaxf(m, h[(size_t)node * HDIM + c]);
    __shared__ float s[256];
    s[t] = m;
    __syncthreads();
    for (int d = 128; d >= 16; d >>= 1) {
        if (t < d) s[t] = fmaxf(s[t], s[t + d]);
        __syncthreads();
    }
    if (t < 16) atomicMax(&pooled[t], __float_as_uint(s[t]));
}

// out[a] = sum_c pooled[c] * Wc[c][a] + bc[a]   (Wc: [16,10])
__global__ void k_final(const unsigned int* __restrict__ pooled, const float* __restrict__ Wc,
                        const float* __restrict__ bc, float* __restrict__ out) {
    __shared__ float p[HDIM];
    int t = threadIdx.x;
    if (t < HDIM) p[t] = __uint_as_float(pooled[t]);
    __syncthreads();
    if (t < AOUT) {
        float acc = bc[t];
#pragma unroll
        for (int c = 0; c < HDIM; c++) acc += p[c] * Wc[c * AOUT + t];
        out[t] = acc;
    }
}

extern "C" void kernel_launch(void* const* d_in, const int* in_sizes, int n_in,
                              void* d_out, int out_size, void* d_ws, size_t ws_size,
                              hipStream_t stream) {
    const float* x  = (const float*)d_in[0];
    const int*   ei = (const int*)d_in[1];
    const float* W1 = (const float*)d_in[2];
    const float* b1 = (const float*)d_in[3];
    const float* W2 = (const float*)d_in[4];
    const float* b2 = (const float*)d_in[5];
    const float* Wc = (const float*)d_in[6];
    const float* bc = (const float*)d_in[7];
    float* out = (float*)d_out;

    int n = in_sizes[0] / FIN;
    int E = in_sizes[1] / 2;
    const int* srcp = ei;       // edge_index[0]
    const int* dstp = ei + E;   // edge_index[1]
    int K = (n + NPB - 1) / NPB;   // 391 for n=100000

    char* ws = (char*)d_ws;
    auto alloc = [&](size_t bytes) -> char* {
        char* p = ws;
        ws += (bytes + 255) & ~(size_t)255;
        return p;
    };
    float*        dis   = (float*)alloc((size_t)n * 4);
    int*          bcnt  = (int*)alloc((size_t)K * 4);
    int*          pbase = (int*)alloc((size_t)K * 4);
    int*          ebase = (int*)alloc((size_t)K * 4);
    int*          bcur  = (int*)alloc((size_t)K * 4);
    int*          off   = (int*)alloc((size_t)(n + 1) * 4);
    unsigned int* pairs = (unsigned int*)alloc(((size_t)E + (size_t)K * 16) * 4);
    int*          srcidx= (int*)alloc((size_t)E * 4);
    float*        g     = (float*)alloc((size_t)n * HDIM * 4);
    float*        h     = (float*)alloc((size_t)n * HDIM * 4);
    unsigned int* pooled= (unsigned int*)alloc(64);

    hipMemsetAsync(bcnt, 0, (size_t)K * 4, stream);
    hipMemsetAsync(pooled, 0, 64, stream);

    k_bcount<<<512, 256, 0, stream>>>(dstp, E, bcnt, K);
    k_bscan<<<1, 256, 0, stream>>>(bcnt, pbase, ebase, bcur, off, K, n, E);
    k_bin<<<(E + TILE - 1) / TILE, 256, 0, stream>>>(srcp, dstp, E, bcur, pairs, K);
    k_sort<<<K, 256, 0, stream>>>(pairs, pbase, ebase, bcnt, srcidx, off, dis, n);

    k_gemm1<<<(n + 15) / 16, 256, 0, stream>>>(x, W1, dis, g, n);
    k_agg<<<(n + 3) / 4, 256, 0, stream>>>((const float4*)g, off, srcidx, dis,
                                           (const float4*)b1, (float4*)h, n);
    k_gemm2<<<(n + 15) / 16, 256, 0, stream>>>(h, W2, dis, g, n);
    k_agg<<<(n + 3) / 4, 256, 0, stream>>>((const float4*)g, off, srcidx, dis,
                                           (const float4*)b2, (float4*)h, n);

    k_maxpool<<<256, 256, 0, stream>>>(h, pooled, n);
    k_final<<<1, 64, 0, stream>>>(pooled, Wc, bc, out);
}